// Round 7
// baseline (468.545 us; speedup 1.0000x reference)
//
#include <hip/hip_runtime.h>

typedef float f4 __attribute__((ext_vector_type(4)));

namespace {
constexpr int NZ = 48, NY = 256, NX = 512;
constexpr int SY = NX;            // y stride (elements)
constexpr int SZ = NX * NY;       // z stride (elements)
constexpr int NTOT = NZ * NY * NX;
constexpr float INV_DX = 1.0f / 100000.0f;
constexpr float INV_DY = 1.0f / 100000.0f;
constexpr float INV_DZ = 1.0f / 500.0f;
}

__device__ __forceinline__ f4 sp(float s) { return (f4){s, s, s, s}; }

__device__ __forceinline__ f4 ldv(const float* __restrict__ f, int e) {
    return *reinterpret_cast<const f4*>(f + e);
}

// ---- x-axis: per-element window [L | C | R]; thread covers i = x0..x0+3 ----
__device__ __forceinline__ void grad2x(f4 L, f4 C, f4 R, int x0, float inv_h,
                                       f4& g, f4& gg) {
    const float h1 = inv_h, h2 = 0.5f * inv_h;
    float win[12] = {L[0], L[1], L[2], L[3], C[0], C[1], C[2], C[3],
                     R[0], R[1], R[2], R[3]};
#pragma unroll
    for (int j = 0; j < 4; ++j) {
        g[j]  = (win[5 + j] - win[3 + j]) * h2;
        gg[j] = ((win[6 + j] - win[4 + j]) * h2 - (win[4 + j] - win[2 + j]) * h2) * h2;
    }
    if (x0 == 0) {
        g[0]  = (C[1] - C[0]) * h1;
        gg[0] = ((C[2] - C[0]) * h2 - g[0]) * h1;
        gg[1] = ((C[3] - C[1]) * h2 - (C[1] - C[0]) * h1) * h2;
    } else if (x0 == NX - 4) {
        gg[2] = ((C[3] - C[2]) * h1 - (C[2] - C[0]) * h2) * h2;
        g[3]  = (C[3] - C[2]) * h1;
        gg[3] = (g[3] - (C[3] - C[1]) * h2) * h1;
    }
}

__device__ __forceinline__ f4 grad1x(f4 L, f4 C, f4 R, int x0, float inv_h) {
    const float h1 = inv_h, h2 = 0.5f * inv_h;
    f4 g;
    g[0] = (C[1] - L[3]) * h2;
    g[1] = (C[2] - C[0]) * h2;
    g[2] = (C[3] - C[1]) * h2;
    g[3] = (R[0] - C[2]) * h2;
    if (x0 == 0)            g[0] = (C[1] - C[0]) * h1;
    else if (x0 == NX - 4)  g[3] = (C[3] - C[2]) * h1;
    return g;
}

// ---- y/z axes: whole-vector stencil, index i uniform across the f4 ----
__device__ __forceinline__ void grad2v(f4 m2, f4 m1, f4 c, f4 p1, f4 p2,
                                       int i, int n, float inv_h, f4& g, f4& gg) {
    const float h1 = inv_h, h2 = 0.5f * inv_h;
    if (i >= 2 && i <= n - 3) {
        g  = (p1 - m1) * sp(h2);
        gg = ((p2 - c) * sp(h2) - (c - m2) * sp(h2)) * sp(h2);
    } else if (i == 0) {
        g  = (p1 - c) * sp(h1);
        gg = ((p2 - c) * sp(h2) - g) * sp(h1);
    } else if (i == 1) {
        g  = (p1 - m1) * sp(h2);
        gg = ((p2 - c) * sp(h2) - (c - m1) * sp(h1)) * sp(h2);
    } else if (i == n - 2) {
        g  = (p1 - m1) * sp(h2);
        gg = ((p1 - c) * sp(h1) - (c - m2) * sp(h2)) * sp(h2);
    } else { // i == n-1
        g  = (c - m1) * sp(h1);
        gg = (g - (c - m2) * sp(h2)) * sp(h1);
    }
}

__device__ __forceinline__ f4 grad1v(f4 m1, f4 c, f4 p1, int i, int n, float inv_h) {
    if (i == 0)     return (p1 - c) * sp(inv_h);
    if (i == n - 1) return (c - m1) * sp(inv_h);
    return (p1 - m1) * sp(0.5f * inv_h);
}

struct Offs {
    int xm, xp;
    int m1y, m2y, p1y, p2y;
    int m1z, m2z, p1z, p2z;
    int x0, y, z;
};

__device__ __forceinline__ Offs make_offs(int x0, int y, int z) {
    Offs o;
    o.x0 = x0; o.y = y; o.z = z;
    o.xm = (x0 > 0) ? -4 : 0;
    o.xp = (x0 < NX - 4) ? 4 : 0;
    o.m1y = (y > 0) ? -SY : 0;
    o.m2y = (y > 1) ? -2 * SY : o.m1y;
    o.p1y = (y < NY - 1) ? SY : 0;
    o.p2y = (y < NY - 2) ? 2 * SY : o.p1y;
    o.m1z = (z > 0) ? -SZ : 0;
    o.m2z = (z > 1) ? -2 * SZ : o.m1z;
    o.p1z = (z < NZ - 1) ? SZ : 0;
    o.p2z = (z < NZ - 2) ? 2 * SZ : o.p1z;
    return o;
}

__device__ __forceinline__ void field_grad2(const float* __restrict__ f, int e,
                                            const Offs& o, f4 C,
                                            f4& gx, f4& gy, f4& gz, f4& lap) {
    f4 L = ldv(f, e + o.xm);
    f4 R = ldv(f, e + o.xp);
    f4 gg;
    grad2x(L, C, R, o.x0, INV_DX, gx, gg);
    lap = gg;
    grad2v(ldv(f, e + o.m2y), ldv(f, e + o.m1y), C, ldv(f, e + o.p1y),
           ldv(f, e + o.p2y), o.y, NY, INV_DY, gy, gg);
    lap += gg;
    grad2v(ldv(f, e + o.m2z), ldv(f, e + o.m1z), C, ldv(f, e + o.p1z),
           ldv(f, e + o.p2z), o.z, NZ, INV_DZ, gz, gg);
    lap += gg;
}

__device__ __forceinline__ void field_grad1(const float* __restrict__ f, int e,
                                            const Offs& o, f4 C,
                                            f4& gx, f4& gy, f4& gz) {
    f4 L = ldv(f, e + o.xm);
    f4 R = ldv(f, e + o.xp);
    gx = grad1x(L, C, R, o.x0, INV_DX);
    gy = grad1v(ldv(f, e + o.m1y), C, ldv(f, e + o.p1y), o.y, NY, INV_DY);
    gz = grad1v(ldv(f, e + o.m1z), C, ldv(f, e + o.p1z), o.z, NZ, INV_DZ);
}

// ============ one launch, two wave roles, co-resident on the same XCD ======
// bid layout: [j : 10][role : 1][xcd : 3]  -> same (j,xcd) pair of roles is
// 8 launch slots apart (co-resident in time, same XCD L2 under round-robin).
__global__ __launch_bounds__(256, 6)
void pe_roles(const float* __restrict__ u, const float* __restrict__ v,
              const float* __restrict__ w, const float* __restrict__ T,
              const float* __restrict__ q, const float* __restrict__ p,
              const float* __restrict__ rho,
              const float* __restrict__ F_u, const float* __restrict__ F_v,
              const float* __restrict__ F_w, const float* __restrict__ Q,
              const float* __restrict__ S,
              const float* __restrict__ nu_p, const float* __restrict__ kappa_p,
              float* __restrict__ out) {
    const int bid = blockIdx.x;
    const int xcd = bid & 7;
    const int role = (bid >> 3) & 1;
    const int j = bid >> 4;                        // 0..767
    const int z = j >> 4;                          // 0..47
    const int yp = (xcd << 4) | (j & 15);          // y-pair 0..127
    const int y = (yp << 1) | (threadIdx.x >> 7);  // row 0..255
    const int x0 = (threadIdx.x & 127) << 2;
    const int e = z * SZ + y * SY + x0;
    const Offs o = make_offs(x0, y, z);

    const f4 uc = ldv(u, e);
    const f4 vc = ldv(v, e);
    const f4 wc = ldv(w, e);
    const f4 rhoc = ldv(rho, e);
    const f4 pc = ldv(p, e);

    f4 gx, gy, gz, lap;

    if (role == 0) {
        // ================= momentum: du, dv, dw =================
        const float snu = nu_p[0];
        const float lat = -1.57079632679f + (3.14159265359f / 255.0f) * (float)y;
        const float fc = 2.0f * 7.2921e-5f * __sinf(lat);
        const f4 inv_rs = sp(1.0f) / (rhoc + sp(1e-10f));

        f4 gpx, gpy, gpz;
        field_grad1(p, e, o, pc, gpx, gpy, gpz);

        f4 acc_u = ldv(F_u, e) - gpx * inv_rs + sp(fc) * vc;
        f4 acc_v = ldv(F_v, e) - gpy * inv_rs - sp(fc) * uc;
        f4 acc_w = ldv(F_w, e) - gpz * inv_rs - sp(9.80665f);

        field_grad2(u, e, o, uc, gx, gy, gz, lap);
        acc_u += sp(snu) * lap - (uc * gx + vc * gy + wc * gz);

        field_grad2(v, e, o, vc, gx, gy, gz, lap);
        acc_v += sp(snu) * lap - (uc * gx + vc * gy + wc * gz);

        field_grad2(w, e, o, wc, gx, gy, gz, lap);
        acc_w += sp(snu) * lap - (uc * gx + vc * gy + wc * gz);

        *reinterpret_cast<f4*>(out + 0 * NTOT + e) = acc_u;
        *reinterpret_cast<f4*>(out + 1 * NTOT + e) = acc_v;
        *reinterpret_cast<f4*>(out + 2 * NTOT + e) = acc_w;
    } else {
        // ================= thermo: dT, dq, dp, drho =================
        const float skap = kappa_p[0];
        const f4 Tc = ldv(T, e);

        field_grad2(T, e, o, Tc, gx, gy, gz, lap);
        f4 acc_T = sp(skap) * lap - (uc * gx + vc * gy + wc * gz);

        const f4 dp_dz = grad1v(ldv(p, e + o.m1z), pc, ldv(p, e + o.p1z),
                                z, NZ, INV_DZ);
        acc_T += sp(287.0f / 1004.0f) * Tc * wc * dp_dz / (pc + sp(1e-10f));
        acc_T += ldv(Q, e) * sp(1.0f / 1004.0f);

        const f4 qc = ldv(q, e);
        field_grad1(q, e, o, qc, gx, gy, gz);
        f4 acc_q = ldv(S, e) - (uc * gx + vc * gy + wc * gz);

        const f4 du_dx = grad1x(ldv(u, e + o.xm), uc, ldv(u, e + o.xp),
                                x0, INV_DX);
        const f4 dv_dy = grad1v(ldv(v, e + o.m1y), vc, ldv(v, e + o.p1y),
                                y, NY, INV_DY);
        const f4 dw_dz = grad1v(ldv(w, e + o.m1z), wc, ldv(w, e + o.p1z),
                                z, NZ, INV_DZ);
        const f4 div = du_dx + dv_dy + dw_dz;

        field_grad1(rho, e, o, rhoc, gx, gy, gz);
        const f4 acc_rho = -rhoc * div - uc * gx - vc * gy - wc * gz;

        const f4 acc_p = sp(287.0f) * (rhoc * acc_T + Tc * acc_rho);

        *reinterpret_cast<f4*>(out + 3 * NTOT + e) = acc_T;
        *reinterpret_cast<f4*>(out + 4 * NTOT + e) = acc_q;
        *reinterpret_cast<f4*>(out + 5 * NTOT + e) = acc_p;
        *reinterpret_cast<f4*>(out + 6 * NTOT + e) = acc_rho;
    }
}

extern "C" void kernel_launch(void* const* d_in, const int* in_sizes, int n_in,
                              void* d_out, int out_size, void* d_ws, size_t ws_size,
                              hipStream_t stream) {
    const float* u     = (const float*)d_in[0];
    const float* v     = (const float*)d_in[1];
    const float* w     = (const float*)d_in[2];
    const float* T     = (const float*)d_in[3];
    const float* q     = (const float*)d_in[4];
    const float* p     = (const float*)d_in[5];
    const float* rho   = (const float*)d_in[6];
    const float* F_u   = (const float*)d_in[7];
    const float* F_v   = (const float*)d_in[8];
    const float* F_w   = (const float*)d_in[9];
    const float* Q     = (const float*)d_in[10];
    const float* S     = (const float*)d_in[11];
    const float* nu    = (const float*)d_in[12];
    const float* kappa = (const float*)d_in[13];
    float* out = (float*)d_out;

    // 768 tiles/XCD * 2 roles * 8 XCDs = 12288 blocks
    pe_roles<<<12288, 256, 0, stream>>>(u, v, w, T, q, p, rho,
                                        F_u, F_v, F_w, Q, S, nu, kappa, out);
}

// Round 8
// 330.218 us; speedup vs baseline: 1.4189x; 1.4189x over previous
//
#include <hip/hip_runtime.h>

typedef float f2 __attribute__((ext_vector_type(2)));

namespace {
constexpr int NZ = 48, NY = 256, NX = 512;
constexpr int SY = NX;            // y stride (elements)
constexpr int SZ = NX * NY;       // z stride (elements)
constexpr int NTOT = NZ * NY * NX;
constexpr float INV_DX = 1.0f / 100000.0f;
constexpr float INV_DY = 1.0f / 100000.0f;
constexpr float INV_DZ = 1.0f / 500.0f;
}

__device__ __forceinline__ f2 sp(float s) { return (f2){s, s}; }

__device__ __forceinline__ f2 ldv(const float* __restrict__ f, int e) {
    return *reinterpret_cast<const f2*>(f + e);
}

// ---- x-axis: window [L | C | R] of f2; thread covers i = x0, x0+1 ----
__device__ __forceinline__ void grad2x(f2 L, f2 C, f2 R, int x0, float inv_h,
                                       f2& g, f2& gg) {
    const float h1 = inv_h, h2 = 0.5f * inv_h;
    // interior: g_i = (x_{i+1}-x_{i-1})/2h ; gg_i = ((x_{i+2}-x_i)/2h - (x_i-x_{i-2})/2h)/2h
    g[0]  = (C[1] - L[1]) * h2;
    g[1]  = (R[0] - C[0]) * h2;
    gg[0] = ((R[0] - C[0]) * h2 - (C[0] - L[0]) * h2) * h2;
    gg[1] = ((R[1] - C[1]) * h2 - (C[1] - L[1]) * h2) * h2;
    if (x0 == 0) {                       // i==0, i==1
        g[0]  = (C[1] - C[0]) * h1;
        gg[0] = ((R[0] - C[0]) * h2 - g[0]) * h1;
        gg[1] = ((R[1] - C[1]) * h2 - (C[1] - C[0]) * h1) * h2;
    } else if (x0 == NX - 2) {           // i==n-2, i==n-1
        gg[0] = ((C[1] - C[0]) * h1 - (C[0] - L[0]) * h2) * h2;
        g[1]  = (C[1] - C[0]) * h1;
        gg[1] = (g[1] - (C[1] - L[1]) * h2) * h1;
    }
}

__device__ __forceinline__ f2 grad1x(f2 L, f2 C, f2 R, int x0, float inv_h) {
    const float h1 = inv_h, h2 = 0.5f * inv_h;
    f2 g;
    g[0] = (C[1] - L[1]) * h2;
    g[1] = (R[0] - C[0]) * h2;
    if (x0 == 0)            g[0] = (C[1] - C[0]) * h1;
    else if (x0 == NX - 2)  g[1] = (C[1] - C[0]) * h1;
    return g;
}

// ---- y/z axes: whole-vector stencil, index i uniform across the f2 ----
__device__ __forceinline__ void grad2v(f2 m2, f2 m1, f2 c, f2 p1, f2 p2,
                                       int i, int n, float inv_h, f2& g, f2& gg) {
    const float h1 = inv_h, h2 = 0.5f * inv_h;
    if (i >= 2 && i <= n - 3) {
        g  = (p1 - m1) * sp(h2);
        gg = ((p2 - c) * sp(h2) - (c - m2) * sp(h2)) * sp(h2);
    } else if (i == 0) {
        g  = (p1 - c) * sp(h1);
        gg = ((p2 - c) * sp(h2) - g) * sp(h1);
    } else if (i == 1) {
        g  = (p1 - m1) * sp(h2);
        gg = ((p2 - c) * sp(h2) - (c - m1) * sp(h1)) * sp(h2);
    } else if (i == n - 2) {
        g  = (p1 - m1) * sp(h2);
        gg = ((p1 - c) * sp(h1) - (c - m2) * sp(h2)) * sp(h2);
    } else { // i == n-1
        g  = (c - m1) * sp(h1);
        gg = (g - (c - m2) * sp(h2)) * sp(h1);
    }
}

__device__ __forceinline__ f2 grad1v(f2 m1, f2 c, f2 p1, int i, int n, float inv_h) {
    if (i == 0)     return (p1 - c) * sp(inv_h);
    if (i == n - 1) return (c - m1) * sp(inv_h);
    return (p1 - m1) * sp(0.5f * inv_h);
}

struct Offs {
    int xm, xp;
    int m1y, m2y, p1y, p2y;
    int m1z, m2z, p1z, p2z;
    int x0, y, z;
};

__device__ __forceinline__ Offs make_offs(int x0, int y, int z) {
    Offs o;
    o.x0 = x0; o.y = y; o.z = z;
    o.xm = (x0 > 0) ? -2 : 0;
    o.xp = (x0 < NX - 2) ? 2 : 0;
    o.m1y = (y > 0) ? -SY : 0;
    o.m2y = (y > 1) ? -2 * SY : o.m1y;
    o.p1y = (y < NY - 1) ? SY : 0;
    o.p2y = (y < NY - 2) ? 2 * SY : o.p1y;
    o.m1z = (z > 0) ? -SZ : 0;
    o.m2z = (z > 1) ? -2 * SZ : o.m1z;
    o.p1z = (z < NZ - 1) ? SZ : 0;
    o.p2z = (z < NZ - 2) ? 2 * SZ : o.p1z;
    return o;
}

__device__ __forceinline__ void field_grad2(const float* __restrict__ f, int e,
                                            const Offs& o, f2 C,
                                            f2& gx, f2& gy, f2& gz, f2& lap) {
    f2 L = ldv(f, e + o.xm);
    f2 R = ldv(f, e + o.xp);
    f2 gg;
    grad2x(L, C, R, o.x0, INV_DX, gx, gg);
    lap = gg;
    grad2v(ldv(f, e + o.m2y), ldv(f, e + o.m1y), C, ldv(f, e + o.p1y),
           ldv(f, e + o.p2y), o.y, NY, INV_DY, gy, gg);
    lap += gg;
    grad2v(ldv(f, e + o.m2z), ldv(f, e + o.m1z), C, ldv(f, e + o.p1z),
           ldv(f, e + o.p2z), o.z, NZ, INV_DZ, gz, gg);
    lap += gg;
}

__device__ __forceinline__ void field_grad1(const float* __restrict__ f, int e,
                                            const Offs& o, f2 C,
                                            f2& gx, f2& gy, f2& gz) {
    f2 L = ldv(f, e + o.xm);
    f2 R = ldv(f, e + o.xp);
    gx = grad1x(L, C, R, o.x0, INV_DX);
    gy = grad1v(ldv(f, e + o.m1y), C, ldv(f, e + o.p1y), o.y, NY, INV_DY);
    gz = grad1v(ldv(f, e + o.m1z), C, ldv(f, e + o.p1z), o.z, NZ, INV_DZ);
}

// r3-winning fused structure + XCD y-band map, float2 granularity,
// VGPR capped to 64 (8 waves/SIMD) via launch_bounds.
__global__ __launch_bounds__(256, 8)
void pe_f2(const float* __restrict__ u, const float* __restrict__ v,
           const float* __restrict__ w, const float* __restrict__ T,
           const float* __restrict__ q, const float* __restrict__ p,
           const float* __restrict__ rho,
           const float* __restrict__ F_u, const float* __restrict__ F_v,
           const float* __restrict__ F_w, const float* __restrict__ Q,
           const float* __restrict__ S,
           const float* __restrict__ nu_p, const float* __restrict__ kappa_p,
           float* __restrict__ out) {
    // block = one x-row (256 threads x 2 pts). xcd = bid&7 owns a 32-row
    // y-band for all z, swept z-major (r3's winning L2-locality map).
    const int bid = blockIdx.x;
    const int xcd = bid & 7;
    const int j = bid >> 3;              // 0..1535
    const int z = j >> 5;                // 0..47
    const int y = (xcd << 5) | (j & 31); // 32-row band per XCD
    const int x0 = threadIdx.x << 1;
    const int e = z * SZ + y * SY + x0;
    const Offs o = make_offs(x0, y, z);

    const float snu = nu_p[0];
    const float skap = kappa_p[0];
    const float lat = -1.57079632679f + (3.14159265359f / 255.0f) * (float)y;
    const float fc = 2.0f * 7.2921e-5f * __sinf(lat);

    const f2 uc = ldv(u, e);
    const f2 vc = ldv(v, e);
    const f2 wc = ldv(w, e);

    f2 gx, gy, gz, lap;

    // ---- u ----
    field_grad2(u, e, o, uc, gx, gy, gz, lap);
    const f2 du_dx = gx;
    f2 acc_u = sp(snu) * lap - (uc * gx + vc * gy + wc * gz);

    // ---- v ----
    field_grad2(v, e, o, vc, gx, gy, gz, lap);
    const f2 dv_dy = gy;
    f2 acc_v = sp(snu) * lap - (uc * gx + vc * gy + wc * gz);

    // ---- w ----
    field_grad2(w, e, o, wc, gx, gy, gz, lap);
    const f2 dw_dz = gz;
    f2 acc_w = sp(snu) * lap - (uc * gx + vc * gy + wc * gz);

    const f2 div = du_dx + dv_dy + dw_dz;

    // ---- T ----
    const f2 Tc = ldv(T, e);
    field_grad2(T, e, o, Tc, gx, gy, gz, lap);
    f2 acc_T = sp(skap) * lap - (uc * gx + vc * gy + wc * gz);

    // ---- rho (grad1) ----
    const f2 rhoc = ldv(rho, e);
    field_grad1(rho, e, o, rhoc, gx, gy, gz);
    const f2 acc_rho = -rhoc * div - uc * gx - vc * gy - wc * gz;

    // ---- p (grad1) ----
    const f2 pc = ldv(p, e);
    field_grad1(p, e, o, pc, gx, gy, gz);
    const f2 inv_rs = sp(1.0f) / (rhoc + sp(1e-10f));
    acc_u -= gx * inv_rs;
    acc_v -= gy * inv_rs;
    acc_w -= gz * inv_rs;
    acc_T += sp(287.0f / 1004.0f) * Tc * wc * gz / (pc + sp(1e-10f));

    // ---- q (grad1) ----
    const f2 qc = ldv(q, e);
    field_grad1(q, e, o, qc, gx, gy, gz);
    f2 acc_q = -(uc * gx + vc * gy + wc * gz);

    // ---- Coriolis / forcings / sources ----
    acc_u += sp(fc) * vc + ldv(F_u, e);
    acc_v += ldv(F_v, e) - sp(fc) * uc;
    acc_w += ldv(F_w, e) - sp(9.80665f);
    acc_T += ldv(Q, e) * sp(1.0f / 1004.0f);
    acc_q += ldv(S, e);

    const f2 acc_p = sp(287.0f) * (rhoc * acc_T + Tc * acc_rho);

    *reinterpret_cast<f2*>(out + 0 * NTOT + e) = acc_u;
    *reinterpret_cast<f2*>(out + 1 * NTOT + e) = acc_v;
    *reinterpret_cast<f2*>(out + 2 * NTOT + e) = acc_w;
    *reinterpret_cast<f2*>(out + 3 * NTOT + e) = acc_T;
    *reinterpret_cast<f2*>(out + 4 * NTOT + e) = acc_q;
    *reinterpret_cast<f2*>(out + 5 * NTOT + e) = acc_p;
    *reinterpret_cast<f2*>(out + 6 * NTOT + e) = acc_rho;
}

extern "C" void kernel_launch(void* const* d_in, const int* in_sizes, int n_in,
                              void* d_out, int out_size, void* d_ws, size_t ws_size,
                              hipStream_t stream) {
    const float* u     = (const float*)d_in[0];
    const float* v     = (const float*)d_in[1];
    const float* w     = (const float*)d_in[2];
    const float* T     = (const float*)d_in[3];
    const float* q     = (const float*)d_in[4];
    const float* p     = (const float*)d_in[5];
    const float* rho   = (const float*)d_in[6];
    const float* F_u   = (const float*)d_in[7];
    const float* F_v   = (const float*)d_in[8];
    const float* F_w   = (const float*)d_in[9];
    const float* Q     = (const float*)d_in[10];
    const float* S     = (const float*)d_in[11];
    const float* nu    = (const float*)d_in[12];
    const float* kappa = (const float*)d_in[13];
    float* out = (float*)d_out;

    // 48 z * 256 y rows = 12288 blocks (one x-row per block)
    pe_f2<<<12288, 256, 0, stream>>>(u, v, w, T, q, p, rho,
                                     F_u, F_v, F_w, Q, S, nu, kappa, out);
}